// Round 2
// baseline (9675.314 us; speedup 1.0000x reference)
//
#include <hip/hip_runtime.h>
#include <cstdint>
#include <cstddef>

// BooleanReservoir — persistent cooperative kernel.
// lane = batch (64 lanes = 64 batches); states[node] = u64 (bit b = batch b).
// The packed LUT (512 B/node) + masked adjacency live in LDS for all 128 steps;
// only the 160 KB state double-buffer is global. Grid sync = monotone-counter
// barrier with agent-scope atomics + __threadfence release/acquire.

#define N_NODES   20000
#define N_INPUT   64
#define K_MAX     12
#define T_STEPS   128
#define N_BATCH   64
#define N_OUT     10
#define N_FEAT    (N_NODES - N_INPUT)   // 19936
#define DUMMY_NODE 20000                // always-zero state word
#define ST_WORDS  20004

#define NBLK 256
#define NTHR 512                        // 8 waves/block
#define NPB  78                         // nodes per block: 256*78 = 19968 >= 19936
#define NPB_PAD 80                      // 8 waves * 2 passes * 5 nodes

typedef unsigned long long u64;

// ---------------- pack x: xp[t][b] = bits j of x[b][t][j] ----------------
__global__ __launch_bounds__(256) void pack_x_kernel(const int* __restrict__ x,
                                                     u64* __restrict__ xp) {
  const int t = blockIdx.x;
  const int wave = threadIdx.x >> 6, lane = threadIdx.x & 63;
  for (int b = wave; b < N_BATCH; b += 4) {
    int v = x[((size_t)b * T_STEPS + t) * 64 + lane];
    u64 bal = __ballot(v != 0);
    if (lane == 0) xp[(size_t)t * N_BATCH + b] = bal;
  }
}

// -------- init state buffers, wcol, u(0), barrier counter --------
__global__ __launch_bounds__(256) void init_kernel(const int* __restrict__ inis,
                                                   const int* __restrict__ w_in,
                                                   const u64* __restrict__ xp,
                                                   u64* __restrict__ buf0,
                                                   u64* __restrict__ buf1,
                                                   u64* __restrict__ wcol,
                                                   unsigned* __restrict__ bar) {
  if (blockIdx.x < 79) {
    int n = blockIdx.x * 256 + threadIdx.x;
    if (n >= N_INPUT && n < ST_WORDS) {
      u64 w = (n < N_NODES && inis[n] != 0) ? ~0ull : 0ull;   // dummy/pad -> 0
      buf0[n] = w;
      buf1[n] = w;   // no-neigh nodes never rewritten: init lives in both buffers
    }
  } else {
    // block 79: wcol[i] = bits j of w_in[j][i]; u(0) -> buf0[0..63]; zero barrier
    const int wave = threadIdx.x >> 6, lane = threadIdx.x & 63;
    u64 xw = xp[lane];                       // xp[t=0][b=lane]
    for (int i = wave; i < 64; i += 4) {
      int wv = w_in[(size_t)lane * 64 + i];  // lane = j
      u64 wc = __ballot(wv != 0);
      if (lane == 0) wcol[i] = wc;
      u64 ub = __ballot((xw & wc) != 0);     // u(0)[b][i], lane = b
      if (lane == 0) buf0[i] = ub;
    }
    if (threadIdx.x == 255) *bar = 0u;       // ws re-poisoned each call
  }
}

// ---------------- persistent reservoir: all 128 steps ----------------
__global__ __launch_bounds__(NTHR) void reservoir_kernel(
    const int* __restrict__ lut, const int* __restrict__ adj,
    const int* __restrict__ mask, const u64* __restrict__ xp,
    const u64* __restrict__ wcol, u64* __restrict__ buf0,
    u64* __restrict__ buf1, unsigned* __restrict__ bar) {
  __shared__ u64 lut_lds[NPB_PAD * 64];        // 40960 B
  __shared__ int adj_lds[NPB_PAD * K_MAX];     //  3840 B
  __shared__ unsigned char hn_lds[NPB_PAD];
  __shared__ u64 scratch[8][64];               //  4096 B
  __shared__ u64 wcol_lds[64];

  const int bi = blockIdx.x;
  const int tid = threadIdx.x;
  const int wave = tid >> 6, lane = tid & 63;
  const int base = N_INPUT + bi * NPB;
  const int nloc = min(NPB, N_NODES - base);   // last block: 46

  // ---- prologue: adjacency + has-neighbor into LDS (pad -> DUMMY/0) ----
  if (tid < NPB_PAD) {
    int i = tid, h = 0;
    if (i < nloc) {
      for (int j = 0; j < K_MAX; j++) {
        int m = mask[(size_t)(base + i) * K_MAX + j];
        int a = adj[(size_t)(base + i) * K_MAX + j];
        adj_lds[i * K_MAX + j] = m ? a : DUMMY_NODE;
        h |= m;
      }
    } else {
      for (int j = 0; j < K_MAX; j++) adj_lds[i * K_MAX + j] = DUMMY_NODE;
    }
    hn_lds[i] = (unsigned char)(h ? 1 : 0);
  }
  if (bi == NBLK - 1 && tid < 64) wcol_lds[tid] = wcol[tid];

  // ---- prologue: pack this block's LUT slice into LDS ----
  // word widx = node (widx>>6), 64-entry group (widx&63); addr monotone in widx.
  const int nwords = nloc * 64;
  const int* lp = lut + (size_t)base * 4096;
  for (int w0 = wave * 8; w0 < nwords; w0 += 64) {
    int v[8];
#pragma unroll
    for (int q = 0; q < 8; q++) {              // 8 loads in flight per wave
      int widx = w0 + q;
      v[q] = (widx < nwords) ? lp[(size_t)widx * 64 + lane] : 0;
    }
#pragma unroll
    for (int q = 0; q < 8; q++) {
      int widx = w0 + q;
      u64 bal = __ballot(v[q] != 0);
      if (lane == 0 && widx < nwords) lut_lds[widx] = bal;
    }
  }
  __syncthreads();   // LDS ready (block-local; no grid sync needed before step 0)

  // ---- 128 steps ----
  for (int t = 0; t < T_STEPS; t++) {
    const u64* cur = (t & 1) ? buf1 : buf0;
    u64* nxt       = (t & 1) ? buf0 : buf1;

    // issue all state gathers up front (2 passes x 60 lanes)
    u64 nb[2];
    int l0arr[2];
#pragma unroll
    for (int p = 0; p < 2; p++) {
      const int l0 = (p * 8 + wave) * 5;       // 0..75
      l0arr[p] = l0;
      u64 v = 0;
      if (lane < 60) {
        int a = adj_lds[l0 * K_MAX + lane];    // pad slots hold DUMMY
        v = cur[a];                            // random gather (L3)
      }
      nb[p] = v;
    }

#pragma unroll
    for (int p = 0; p < 2; p++) {
      const int l0 = l0arr[p];
      scratch[wave][lane] = nb[p];             // wave-internal
      const int cnt = min(5, nloc - l0);       // may be <= 0
#pragma unroll
      for (int i = 0; i < 5; i++) {
        if (i < cnt) {                         // wave-uniform
          unsigned idx = 0;
#pragma unroll
          for (int j = 0; j < K_MAX; j++) {
            u64 w = scratch[wave][i * K_MAX + j];            // broadcast
            idx = (idx << 1) | (unsigned)((w >> lane) & 1ull); // MSB-first
          }
          u64 g = lut_lds[(l0 + i) * 64 + (idx >> 6)];
          u64 res = __ballot((g >> (idx & 63)) & 1ull);
          if (lane == 0 && hn_lds[l0 + i]) nxt[base + l0 + i] = res;
        }
      }
    }

    // u(t+1) -> nxt[0..63]: block 255 wave 7 (its pass-1 slots are padding)
    if (bi == NBLK - 1 && wave == 7 && t + 1 < T_STEPS) {
      u64 xw = xp[(size_t)(t + 1) * N_BATCH + lane];         // lane = batch
      for (int i = 0; i < 64; i++) {
        u64 ub = __ballot((xw & wcol_lds[i]) != 0);
        if (lane == 0) nxt[i] = ub;
      }
    }

    // ---- grid barrier (skip after last step; kernel-end release covers it) ----
    if (t != T_STEPS - 1) {
      __syncthreads();
      __threadfence();          // per-wave release: drain stores + writeback L2
      __syncthreads();
      if (tid == 0) {
        __hip_atomic_fetch_add(bar, 1u, __ATOMIC_RELAXED, __HIP_MEMORY_SCOPE_AGENT);
        const unsigned target = (unsigned)NBLK * (unsigned)(t + 1);
        while (__hip_atomic_load(bar, __ATOMIC_RELAXED, __HIP_MEMORY_SCOPE_AGENT) < target)
          __builtin_amdgcn_s_sleep(2);
      }
      __syncthreads();
      __threadfence();          // acquire: invalidate stale L1/L2 before next reads
    }
  }
}

// ---------------- readout: sigmoid(feats @ W_out^T + b_out) ----------------
__global__ __launch_bounds__(256) void readout_kernel(const u64* __restrict__ st,
                                                      const float* __restrict__ Wout,
                                                      const float* __restrict__ bout,
                                                      float* __restrict__ out) {
  const int b = blockIdx.x / N_OUT;
  const int o = blockIdx.x % N_OUT;
  float acc = 0.f;
  for (int n = threadIdx.x; n < N_FEAT; n += 256) {
    u64 s = st[N_INPUT + n];
    float w = Wout[(size_t)o * N_FEAT + n];
    acc += ((s >> b) & 1ull) ? w : 0.f;
  }
  for (int off = 32; off > 0; off >>= 1) acc += __shfl_down(acc, off);
  __shared__ float red[4];
  const int wave = threadIdx.x >> 6, lane = threadIdx.x & 63;
  if (lane == 0) red[wave] = acc;
  __syncthreads();
  if (threadIdx.x == 0) {
    float tot = red[0] + red[1] + red[2] + red[3] + bout[o];
    out[(size_t)b * N_OUT + o] = 1.f / (1.f + __expf(-tot));
  }
}

extern "C" void kernel_launch(void* const* d_in, const int* in_sizes, int n_in,
                              void* d_out, int out_size, void* d_ws, size_t ws_size,
                              hipStream_t stream) {
  const int* x    = (const int*)d_in[0];
  const int* w_in = (const int*)d_in[1];
  const int* adj  = (const int*)d_in[2];
  const int* mask = (const int*)d_in[3];
  const int* lut  = (const int*)d_in[4];
  const int* inis = (const int*)d_in[5];
  const float* Wout = (const float*)d_in[6];
  const float* bout = (const float*)d_in[7];
  float* out = (float*)d_out;

  char* ws = (char*)d_ws;
  size_t off = 0;
  auto alloc = [&](size_t bytes) -> void* {
    void* p = ws + off;
    off += (bytes + 255) & ~(size_t)255;
    return p;
  };
  u64* buf0 = (u64*)alloc((size_t)ST_WORDS * 8);
  u64* buf1 = (u64*)alloc((size_t)ST_WORDS * 8);
  u64* xp   = (u64*)alloc((size_t)T_STEPS * N_BATCH * 8);
  u64* wcol = (u64*)alloc(64 * 8);
  unsigned* bar = (unsigned*)alloc(256);       // own cache line
  (void)ws_size; (void)in_sizes; (void)n_in; (void)out_size;

  hipLaunchKernelGGL(pack_x_kernel, dim3(T_STEPS), dim3(256), 0, stream, x, xp);
  hipLaunchKernelGGL(init_kernel, dim3(80), dim3(256), 0, stream,
                     inis, w_in, xp, buf0, buf1, wcol, bar);

  void* args[] = {(void*)&lut, (void*)&adj, (void*)&mask, (void*)&xp,
                  (void*)&wcol, (void*)&buf0, (void*)&buf1, (void*)&bar};
  hipLaunchCooperativeKernel((const void*)reservoir_kernel,
                             dim3(NBLK), dim3(NTHR), args, 0, stream);

  // T even -> final states in buf0
  hipLaunchKernelGGL(readout_kernel, dim3(N_BATCH * N_OUT), dim3(256), 0, stream,
                     buf0, Wout, bout, out);
}

// Round 3
// 1402.274 us; speedup vs baseline: 6.8997x; 6.8997x over previous
//
#include <hip/hip_runtime.h>
#include <cstdint>
#include <cstddef>

// BooleanReservoir — persistent cooperative kernel, fence-free barrier.
// lane = batch; states[node] = u64 (bit b = batch b). Packed LUT + adjacency in
// LDS for all 128 steps. ALL cross-block state traffic uses device-scope relaxed
// atomics (bypass non-coherent L1/L2, complete at Infinity Cache), so the grid
// barrier needs no buffer_wbl2/buffer_inv cache ops (R2's 72 us/step mistake).

#define N_NODES   20000
#define N_INPUT   64
#define K_MAX     12
#define T_STEPS   128
#define N_BATCH   64
#define N_OUT     10
#define N_FEAT    (N_NODES - N_INPUT)   // 19936
#define DUMMY_NODE 20000                // always-zero state word
#define ST_WORDS  20004

#define NBLK 512
#define NTHR 512                        // 8 waves/block, 2 blocks/CU
#define NPB  39                         // nodes/block: 512*39 = 19968 >= 19936
#define NPB_PAD 40                      // 8 waves * 5 nodes
#define BAR_CNT 64                      // distributed barrier counters
#define BAR_STRIDE 32                   // u32 units -> 128 B apart

typedef unsigned long long u64;

// ---------------- pack x: xp[t][b] = bits j of x[b][t][j] ----------------
__global__ __launch_bounds__(256) void pack_x_kernel(const int* __restrict__ x,
                                                     u64* __restrict__ xp) {
  const int t = blockIdx.x;
  const int wave = threadIdx.x >> 6, lane = threadIdx.x & 63;
  for (int b = wave; b < N_BATCH; b += 4) {
    int v = x[((size_t)b * T_STEPS + t) * 64 + lane];
    u64 bal = __ballot(v != 0);
    if (lane == 0) xp[(size_t)t * N_BATCH + b] = bal;
  }
}

// -------- init state buffers, wcol, u(0), barrier counters --------
__global__ __launch_bounds__(256) void init_kernel(const int* __restrict__ inis,
                                                   const int* __restrict__ w_in,
                                                   const u64* __restrict__ xp,
                                                   u64* __restrict__ buf0,
                                                   u64* __restrict__ buf1,
                                                   u64* __restrict__ wcol,
                                                   unsigned* __restrict__ bar) {
  if (blockIdx.x < 79) {
    int n = blockIdx.x * 256 + threadIdx.x;
    if (n >= N_INPUT && n < ST_WORDS) {
      u64 w = (n < N_NODES && inis[n] != 0) ? ~0ull : 0ull;   // dummy/pad -> 0
      buf0[n] = w;
      buf1[n] = w;   // no-neigh nodes never rewritten: init lives in both buffers
    }
  } else {
    const int wave = threadIdx.x >> 6, lane = threadIdx.x & 63;
    u64 xw = xp[lane];                       // xp[t=0][b=lane]
    for (int i = wave; i < 64; i += 4) {
      int wv = w_in[(size_t)lane * 64 + i];  // lane = j
      u64 wc = __ballot(wv != 0);
      if (lane == 0) wcol[i] = wc;
      u64 ub = __ballot((xw & wc) != 0);     // u(0)[b][i], lane = b
      if (lane == 0) buf0[i] = ub;
    }
    if (threadIdx.x < BAR_CNT) bar[threadIdx.x * BAR_STRIDE] = 0u;  // ws poisoned
  }
}

// ---------------- persistent reservoir: all 128 steps ----------------
__global__ __launch_bounds__(NTHR, 4) void reservoir_kernel(
    const int* __restrict__ lut, const int* __restrict__ adj,
    const int* __restrict__ mask, const u64* __restrict__ xp,
    const u64* __restrict__ wcol, u64* __restrict__ buf0,
    u64* __restrict__ buf1, unsigned* __restrict__ bar) {
  __shared__ u64 lut_lds[NPB_PAD * 64];        // 20480 B
  __shared__ int adj_lds[NPB_PAD * K_MAX];     //  1920 B
  __shared__ unsigned char hn_lds[NPB_PAD];
  __shared__ u64 scratch[8][64];               //  4096 B
  __shared__ u64 wcol_lds[64];

  const int bi = blockIdx.x;
  const int tid = threadIdx.x;
  const int wave = tid >> 6, lane = tid & 63;
  const int base = N_INPUT + bi * NPB;
  const int nloc = min(NPB, N_NODES - base);   // last block: 7

  // ---- prologue: adjacency + has-neighbor into LDS (pad -> DUMMY/0) ----
  if (tid < NPB_PAD) {
    int i = tid, h = 0;
    if (i < nloc) {
      for (int j = 0; j < K_MAX; j++) {
        int m = mask[(size_t)(base + i) * K_MAX + j];
        int a = adj[(size_t)(base + i) * K_MAX + j];
        adj_lds[i * K_MAX + j] = m ? a : DUMMY_NODE;
        h |= m;
      }
    } else {
      for (int j = 0; j < K_MAX; j++) adj_lds[i * K_MAX + j] = DUMMY_NODE;
    }
    hn_lds[i] = (unsigned char)(h ? 1 : 0);
  }
  if (bi == NBLK - 1 && tid < 64) wcol_lds[tid] = wcol[tid];

  // ---- prologue: pack this block's LUT slice into LDS ----
  const int nwords = nloc * 64;
  const int* lp = lut + (size_t)base * 4096;
  for (int w0 = wave * 8; w0 < nwords; w0 += 64) {
    int v[8];
#pragma unroll
    for (int q = 0; q < 8; q++) {
      int widx = w0 + q;
      v[q] = (widx < nwords) ? lp[(size_t)widx * 64 + lane] : 0;   // coalesced 256B
    }
#pragma unroll
    for (int q = 0; q < 8; q++) {
      int widx = w0 + q;
      u64 bal = __ballot(v[q] != 0);
      if (lane == 0 && widx < nwords) lut_lds[widx] = bal;
    }
  }
  __syncthreads();   // block-local; step 0 reads init_kernel's buf0 (launch-ordered)

  // ---- 128 steps ----
  for (int t = 0; t < T_STEPS; t++) {
    u64* cur = (t & 1) ? buf1 : buf0;
    u64* nxt = (t & 1) ? buf0 : buf1;

    // gather: lane l -> neighbor word for (node l/12, slot l%12); L3-coherent
    const int l0 = wave * 5;                   // 0..35
    u64 v = 0;
    if (lane < 60) {
      int a = adj_lds[l0 * K_MAX + lane];      // pad slots hold DUMMY
      v = __hip_atomic_load(&cur[a], __ATOMIC_RELAXED, __HIP_MEMORY_SCOPE_AGENT);
    }
    scratch[wave][lane] = v;                   // wave-internal

    const int cnt = min(5, nloc - l0);         // may be <= 0
#pragma unroll
    for (int i = 0; i < 5; i++) {
      if (i < cnt) {                           // wave-uniform
        unsigned idx = 0;
#pragma unroll
        for (int j = 0; j < K_MAX; j++) {
          u64 w = scratch[wave][i * K_MAX + j];              // broadcast read
          idx = (idx << 1) | (unsigned)((w >> lane) & 1ull); // MSB-first
        }
        u64 g = lut_lds[(l0 + i) * 64 + (idx >> 6)];
        u64 res = __ballot((g >> (idx & 63)) & 1ull);
        if (lane == 0 && hn_lds[l0 + i])
          __hip_atomic_store(&nxt[base + l0 + i], res,
                             __ATOMIC_RELAXED, __HIP_MEMORY_SCOPE_AGENT);
      }
    }

    // u(t+1) -> nxt[0..63]: last block's wave 7 (idle there: nloc=7)
    if (bi == NBLK - 1 && wave == 7 && t + 1 < T_STEPS) {
      u64 xw = xp[(size_t)(t + 1) * N_BATCH + lane];         // lane = batch
      for (int i = 0; i < 64; i++) {
        u64 ub = __ballot((xw & wcol_lds[i]) != 0);
        if (lane == 0)
          __hip_atomic_store(&nxt[i], ub,
                             __ATOMIC_RELAXED, __HIP_MEMORY_SCOPE_AGENT);
      }
    }

    // ---- grid barrier: no cache ops (all shared data is L3-coherent atomics) ----
    if (t != T_STEPS - 1) {
      __syncthreads();   // implicit vmcnt(0)/lgkmcnt(0): atomic stores completed at L3
      __builtin_amdgcn_fence(__ATOMIC_RELEASE, "workgroup");  // compiler ordering only
      if (tid == 0)
        __hip_atomic_fetch_add(&bar[(bi & (BAR_CNT - 1)) * BAR_STRIDE], 1u,
                               __ATOMIC_RELAXED, __HIP_MEMORY_SCOPE_AGENT);
      if (wave == 0) {   // lane l polls counter l; 8 arrivals each per step
        const unsigned tgt = (unsigned)(t + 1) * (NBLK / BAR_CNT);
        for (;;) {
          unsigned c = __hip_atomic_load(&bar[lane * BAR_STRIDE],
                                         __ATOMIC_RELAXED, __HIP_MEMORY_SCOPE_AGENT);
          if (__all(c >= tgt)) break;
          __builtin_amdgcn_s_sleep(1);
        }
      }
      __builtin_amdgcn_fence(__ATOMIC_ACQUIRE, "workgroup");  // compiler ordering only
      __syncthreads();
    }
  }
}

// ---------------- readout: sigmoid(feats @ W_out^T + b_out) ----------------
__global__ __launch_bounds__(256) void readout_kernel(const u64* __restrict__ st,
                                                      const float* __restrict__ Wout,
                                                      const float* __restrict__ bout,
                                                      float* __restrict__ out) {
  const int b = blockIdx.x / N_OUT;
  const int o = blockIdx.x % N_OUT;
  float acc = 0.f;
  for (int n = threadIdx.x; n < N_FEAT; n += 256) {
    u64 s = st[N_INPUT + n];
    float w = Wout[(size_t)o * N_FEAT + n];
    acc += ((s >> b) & 1ull) ? w : 0.f;
  }
  for (int off = 32; off > 0; off >>= 1) acc += __shfl_down(acc, off);
  __shared__ float red[4];
  const int wave = threadIdx.x >> 6, lane = threadIdx.x & 63;
  if (lane == 0) red[wave] = acc;
  __syncthreads();
  if (threadIdx.x == 0) {
    float tot = red[0] + red[1] + red[2] + red[3] + bout[o];
    out[(size_t)b * N_OUT + o] = 1.f / (1.f + __expf(-tot));
  }
}

extern "C" void kernel_launch(void* const* d_in, const int* in_sizes, int n_in,
                              void* d_out, int out_size, void* d_ws, size_t ws_size,
                              hipStream_t stream) {
  const int* x    = (const int*)d_in[0];
  const int* w_in = (const int*)d_in[1];
  const int* adj  = (const int*)d_in[2];
  const int* mask = (const int*)d_in[3];
  const int* lut  = (const int*)d_in[4];
  const int* inis = (const int*)d_in[5];
  const float* Wout = (const float*)d_in[6];
  const float* bout = (const float*)d_in[7];
  float* out = (float*)d_out;

  char* ws = (char*)d_ws;
  size_t off = 0;
  auto alloc = [&](size_t bytes) -> void* {
    void* p = ws + off;
    off += (bytes + 255) & ~(size_t)255;
    return p;
  };
  u64* buf0 = (u64*)alloc((size_t)ST_WORDS * 8);
  u64* buf1 = (u64*)alloc((size_t)ST_WORDS * 8);
  u64* xp   = (u64*)alloc((size_t)T_STEPS * N_BATCH * 8);
  u64* wcol = (u64*)alloc(64 * 8);
  unsigned* bar = (unsigned*)alloc((size_t)BAR_CNT * BAR_STRIDE * 4);
  (void)ws_size; (void)in_sizes; (void)n_in; (void)out_size;

  hipLaunchKernelGGL(pack_x_kernel, dim3(T_STEPS), dim3(256), 0, stream, x, xp);
  hipLaunchKernelGGL(init_kernel, dim3(80), dim3(256), 0, stream,
                     inis, w_in, xp, buf0, buf1, wcol, bar);

  void* args[] = {(void*)&lut, (void*)&adj, (void*)&mask, (void*)&xp,
                  (void*)&wcol, (void*)&buf0, (void*)&buf1, (void*)&bar};
  hipLaunchCooperativeKernel((const void*)reservoir_kernel,
                             dim3(NBLK), dim3(NTHR), args, 0, stream);

  // T even -> final states in buf0
  hipLaunchKernelGGL(readout_kernel, dim3(N_BATCH * N_OUT), dim3(256), 0, stream,
                     buf0, Wout, bout, out);
}

// Round 4
// 1033.248 us; speedup vs baseline: 9.3640x; 1.3572x over previous
//
#include <hip/hip_runtime.h>
#include <cstdint>
#include <cstddef>

// BooleanReservoir — persistent cooperative kernel, v3.
// lane = batch; states[node] = u64 (bit b = batch b). Packed LUT + adjacency in
// LDS for all 128 steps; cross-block state traffic via device-scope relaxed
// atomics (L3-coherent, no cache-maintenance ops).
// R4 changes: (1) 64x64 in-register bit transpose replaces per-bit LDS index
// build (~440 -> ~150 instr/wave/step); (2) hierarchical barrier: 64 arrival
// counters -> leader aggregates -> 8 go-flags (kills 32K-req/round poll storm);
// (3) u(t) precomputed for all t (step-loop copy is 2 instr).

#define N_NODES   20000
#define N_INPUT   64
#define K_MAX     12
#define T_STEPS   128
#define N_BATCH   64
#define N_OUT     10
#define N_FEAT    (N_NODES - N_INPUT)   // 19936
#define DUMMY_NODE 20000                // always-zero state word
#define ST_WORDS  20004

#define NBLK 512
#define NTHR 512                        // 8 waves/block, 2 blocks/CU
#define NPB  39                         // nodes/block: 512*39 = 19968 >= 19936
#define NPB_PAD 40                      // 8 waves * 5 nodes
#define BAR_CNT 64                      // distributed arrival counters
#define GO_CNT  8                       // go-flags (release fan-out)
#define BAR_STRIDE 32                   // u32 units -> 128 B apart

typedef unsigned long long u64;

// ---------------- pack x: xp[t][b] = bits j of x[b][t][j] ----------------
__global__ __launch_bounds__(256) void pack_x_kernel(const int* __restrict__ x,
                                                     u64* __restrict__ xp) {
  const int t = blockIdx.x;
  const int wave = threadIdx.x >> 6, lane = threadIdx.x & 63;
  for (int b = wave; b < N_BATCH; b += 4) {
    int v = x[((size_t)b * T_STEPS + t) * 64 + lane];
    u64 bal = __ballot(v != 0);
    if (lane == 0) xp[(size_t)t * N_BATCH + b] = bal;
  }
}

// -------- init state buffers, wcol, u(0), barrier counters + go flags --------
__global__ __launch_bounds__(256) void init_kernel(const int* __restrict__ inis,
                                                   const int* __restrict__ w_in,
                                                   const u64* __restrict__ xp,
                                                   u64* __restrict__ buf0,
                                                   u64* __restrict__ buf1,
                                                   u64* __restrict__ wcol,
                                                   unsigned* __restrict__ bar) {
  if (blockIdx.x < 79) {
    int n = blockIdx.x * 256 + threadIdx.x;
    if (n >= N_INPUT && n < ST_WORDS) {
      u64 w = (n < N_NODES && inis[n] != 0) ? ~0ull : 0ull;   // dummy/pad -> 0
      buf0[n] = w;
      buf1[n] = w;   // no-neigh nodes never rewritten: init lives in both buffers
    }
  } else {
    const int wave = threadIdx.x >> 6, lane = threadIdx.x & 63;
    u64 xw = xp[lane];                       // xp[t=0][b=lane]
    for (int i = wave; i < 64; i += 4) {
      int wv = w_in[(size_t)lane * 64 + i];  // lane = j
      u64 wc = __ballot(wv != 0);
      if (lane == 0) wcol[i] = wc;
      u64 ub = __ballot((xw & wc) != 0);     // u(0)[b][i], lane = b
      if (lane == 0) buf0[i] = ub;
    }
    if (threadIdx.x < BAR_CNT + GO_CNT)      // ws re-poisoned each call
      bar[threadIdx.x * BAR_STRIDE] = 0u;
  }
}

// -------- precompute u(t) for all t: u_all[t*64+i] bit b = (xp[t][b].wcol[i]) --------
__global__ __launch_bounds__(64) void u_pre_kernel(const u64* __restrict__ xp,
                                                   const u64* __restrict__ wcol,
                                                   u64* __restrict__ u_all) {
  const int t = blockIdx.x, lane = threadIdx.x;
  u64 xw = xp[(size_t)t * N_BATCH + lane];   // lane = batch
  for (int i = 0; i < 64; i++) {
    u64 ub = __ballot((xw & wcol[i]) != 0);
    if (lane == 0) u_all[(size_t)t * 64 + i] = ub;
  }
}

// ---- 64x64 bit transpose: lane l holds row l; returns lane b holding column b ----
__device__ __forceinline__ u64 bit_transpose64(u64 w, int lane) {
  const u64 LO0 = 0x00000000FFFFFFFFull, LO1 = 0x0000FFFF0000FFFFull,
            LO2 = 0x00FF00FF00FF00FFull, LO3 = 0x0F0F0F0F0F0F0F0Full,
            LO4 = 0x3333333333333333ull, LO5 = 0x5555555555555555ull;
#define XP_STAGE(d, LO)                                                  \
  {                                                                      \
    u64 p = (u64)__shfl_xor((long long)w, (d), 64);                      \
    if (lane & (d)) w = ((p >> (d)) & (LO)) | (w & ~(LO));               \
    else            w = (w & (LO)) | ((p << (d)) & ~(LO));               \
  }
  XP_STAGE(32, LO0) XP_STAGE(16, LO1) XP_STAGE(8, LO2)
  XP_STAGE(4,  LO3) XP_STAGE(2,  LO4) XP_STAGE(1, LO5)
#undef XP_STAGE
  return w;
}

// ---------------- persistent reservoir: all 128 steps ----------------
__global__ __launch_bounds__(NTHR, 4) void reservoir_kernel(
    const int* __restrict__ lut, const int* __restrict__ adj,
    const int* __restrict__ mask, const u64* __restrict__ u_all,
    u64* __restrict__ buf0, u64* __restrict__ buf1,
    unsigned* __restrict__ bar) {
  __shared__ u64 lut_lds[NPB_PAD * 64];        // 20480 B
  __shared__ int adj_lds[NPB_PAD * K_MAX];     //  1920 B
  __shared__ unsigned char hn_lds[NPB_PAD];

  const int bi = blockIdx.x;
  const int tid = threadIdx.x;
  const int wave = tid >> 6, lane = tid & 63;
  const int base = N_INPUT + bi * NPB;
  const int nloc = min(NPB, N_NODES - base);   // last block: 7

  // ---- prologue: adjacency (slot-REVERSED: slot j at offset 11-j) + hn ----
  // After transpose, lane b's bit (12i + (11-j)) = neighbor j -> the 12-bit
  // field (w >> 12i) & 0xFFF is directly the reference's MSB-first LUT index.
  if (tid < NPB_PAD) {
    int i = tid, h = 0;
    if (i < nloc) {
      for (int j = 0; j < K_MAX; j++) {
        int m = mask[(size_t)(base + i) * K_MAX + j];
        int a = adj[(size_t)(base + i) * K_MAX + j];
        adj_lds[i * K_MAX + (K_MAX - 1 - j)] = m ? a : DUMMY_NODE;
        h |= m;
      }
    } else {
      for (int j = 0; j < K_MAX; j++) adj_lds[i * K_MAX + j] = DUMMY_NODE;
    }
    hn_lds[i] = (unsigned char)(h ? 1 : 0);
  }

  // ---- prologue: pack this block's LUT slice into LDS (natural entry order) ----
  const int nwords = nloc * 64;
  const int* lp = lut + (size_t)base * 4096;
  for (int w0 = wave * 8; w0 < nwords; w0 += 64) {
    int v[8];
#pragma unroll
    for (int q = 0; q < 8; q++) {
      int widx = w0 + q;
      v[q] = (widx < nwords) ? lp[(size_t)widx * 64 + lane] : 0;   // coalesced 256B
    }
#pragma unroll
    for (int q = 0; q < 8; q++) {
      int widx = w0 + q;
      u64 bal = __ballot(v[q] != 0);
      if (lane == 0 && widx < nwords) lut_lds[widx] = bal;
    }
  }
  __syncthreads();   // block-local; step 0 reads init_kernel's buf0 (launch-ordered)

  const int l0 = wave * 5;                     // this wave's first local node
  const int cnt = min(5, nloc - l0);           // may be <= 0

  // ---- 128 steps ----
  for (int t = 0; t < T_STEPS; t++) {
    u64* cur = (t & 1) ? buf1 : buf0;
    u64* nxt = (t & 1) ? buf0 : buf1;

    // gather: lane l (<60) -> neighbor word for (node l/12, rev-slot l%12)
    u64 w = 0;
    if (lane < 60) {
      int a = adj_lds[l0 * K_MAX + lane];      // pad slots hold DUMMY
      w = __hip_atomic_load(&cur[a], __ATOMIC_RELAXED, __HIP_MEMORY_SCOPE_AGENT);
    }
    // transpose: lane b now holds all 60 index bits for batch b
    w = bit_transpose64(w, lane);

#pragma unroll
    for (int i = 0; i < 5; i++) {
      if (i < cnt) {                           // wave-uniform
        unsigned idx = (unsigned)(w >> (12 * i)) & 0xFFFu;   // MSB-first index
        u64 g = lut_lds[(l0 + i) * 64 + (idx >> 6)];
        u64 res = __ballot((g >> (idx & 63)) & 1ull);
        if (lane == 0 && hn_lds[l0 + i])
          __hip_atomic_store(&nxt[base + l0 + i], res,
                             __ATOMIC_RELAXED, __HIP_MEMORY_SCOPE_AGENT);
      }
    }

    // u(t+1) -> nxt[0..63]: last block's wave 7 (idle there: nloc=7), 64-lane copy
    if (bi == NBLK - 1 && wave == 7 && t + 1 < T_STEPS) {
      u64 uw = u_all[(size_t)(t + 1) * 64 + lane];           // plain coalesced load
      __hip_atomic_store(&nxt[lane], uw, __ATOMIC_RELAXED, __HIP_MEMORY_SCOPE_AGENT);
    }

    // ---- hierarchical grid barrier (no cache-maintenance ops) ----
    if (t != T_STEPS - 1) {
      __syncthreads();   // each wave drains its vmcnt: stores are at L3
      __builtin_amdgcn_fence(__ATOMIC_RELEASE, "workgroup");  // compiler ordering
      if (tid == 0)
        __hip_atomic_fetch_add(&bar[(bi & (BAR_CNT - 1)) * BAR_STRIDE], 1u,
                               __ATOMIC_RELAXED, __HIP_MEMORY_SCOPE_AGENT);
      if (bi == 0 && wave == 0) {
        // leader: lane l polls counter l (one 64-lane load per round)
        const unsigned tgt = (unsigned)(t + 1) * (NBLK / BAR_CNT);
        for (;;) {
          unsigned c = __hip_atomic_load(&bar[lane * BAR_STRIDE],
                                         __ATOMIC_RELAXED, __HIP_MEMORY_SCOPE_AGENT);
          if (__all(c >= tgt)) break;
          __builtin_amdgcn_s_sleep(2);
        }
        if (lane < GO_CNT)
          __hip_atomic_store(&bar[(BAR_CNT + lane) * BAR_STRIDE], (unsigned)(t + 1),
                             __ATOMIC_RELAXED, __HIP_MEMORY_SCOPE_AGENT);
      } else if (wave == 0) {
        // all lanes load the SAME go-flag -> one L3 request per round
        unsigned* gp = &bar[(BAR_CNT + (bi & (GO_CNT - 1))) * BAR_STRIDE];
        while (__hip_atomic_load(gp, __ATOMIC_RELAXED, __HIP_MEMORY_SCOPE_AGENT)
               < (unsigned)(t + 1))
          __builtin_amdgcn_s_sleep(2);
      }
      __builtin_amdgcn_fence(__ATOMIC_ACQUIRE, "workgroup");  // compiler ordering
      __syncthreads();
    }
  }
}

// ---------------- readout: sigmoid(feats @ W_out^T + b_out) ----------------
__global__ __launch_bounds__(256) void readout_kernel(const u64* __restrict__ st,
                                                      const float* __restrict__ Wout,
                                                      const float* __restrict__ bout,
                                                      float* __restrict__ out) {
  const int b = blockIdx.x / N_OUT;
  const int o = blockIdx.x % N_OUT;
  float acc = 0.f;
  for (int n = threadIdx.x; n < N_FEAT; n += 256) {
    u64 s = st[N_INPUT + n];
    float w = Wout[(size_t)o * N_FEAT + n];
    acc += ((s >> b) & 1ull) ? w : 0.f;
  }
  for (int off = 32; off > 0; off >>= 1) acc += __shfl_down(acc, off);
  __shared__ float red[4];
  const int wave = threadIdx.x >> 6, lane = threadIdx.x & 63;
  if (lane == 0) red[wave] = acc;
  __syncthreads();
  if (threadIdx.x == 0) {
    float tot = red[0] + red[1] + red[2] + red[3] + bout[o];
    out[(size_t)b * N_OUT + o] = 1.f / (1.f + __expf(-tot));
  }
}

extern "C" void kernel_launch(void* const* d_in, const int* in_sizes, int n_in,
                              void* d_out, int out_size, void* d_ws, size_t ws_size,
                              hipStream_t stream) {
  const int* x    = (const int*)d_in[0];
  const int* w_in = (const int*)d_in[1];
  const int* adj  = (const int*)d_in[2];
  const int* mask = (const int*)d_in[3];
  const int* lut  = (const int*)d_in[4];
  const int* inis = (const int*)d_in[5];
  const float* Wout = (const float*)d_in[6];
  const float* bout = (const float*)d_in[7];
  float* out = (float*)d_out;

  char* ws = (char*)d_ws;
  size_t off = 0;
  auto alloc = [&](size_t bytes) -> void* {
    void* p = ws + off;
    off += (bytes + 255) & ~(size_t)255;
    return p;
  };
  u64* buf0 = (u64*)alloc((size_t)ST_WORDS * 8);
  u64* buf1 = (u64*)alloc((size_t)ST_WORDS * 8);
  u64* xp   = (u64*)alloc((size_t)T_STEPS * N_BATCH * 8);
  u64* wcol = (u64*)alloc(64 * 8);
  u64* u_all = (u64*)alloc((size_t)T_STEPS * 64 * 8);         // 64 KB
  unsigned* bar = (unsigned*)alloc((size_t)(BAR_CNT + GO_CNT) * BAR_STRIDE * 4);
  (void)ws_size; (void)in_sizes; (void)n_in; (void)out_size;

  hipLaunchKernelGGL(pack_x_kernel, dim3(T_STEPS), dim3(256), 0, stream, x, xp);
  hipLaunchKernelGGL(init_kernel, dim3(80), dim3(256), 0, stream,
                     inis, w_in, xp, buf0, buf1, wcol, bar);
  hipLaunchKernelGGL(u_pre_kernel, dim3(T_STEPS), dim3(64), 0, stream,
                     xp, wcol, u_all);

  void* args[] = {(void*)&lut, (void*)&adj, (void*)&mask, (void*)&u_all,
                  (void*)&buf0, (void*)&buf1, (void*)&bar};
  hipLaunchCooperativeKernel((const void*)reservoir_kernel,
                             dim3(NBLK), dim3(NTHR), args, 0, stream);

  // T even -> final states in buf0
  hipLaunchKernelGGL(readout_kernel, dim3(N_BATCH * N_OUT), dim3(256), 0, stream,
                     buf0, Wout, bout, out);
}